// Round 17
// baseline (176.650 us; speedup 1.0000x reference)
//
#include <hip/hip_runtime.h>
#include <hip/hip_bf16.h>

#define D_BLADE 256
#define D_FFN 1024
#define N_TOK 8192
#define M_TOTAL (N_TOK * 8)

typedef __attribute__((ext_vector_type(8))) short bf16x8;
typedef __attribute__((ext_vector_type(4))) short short4_t;
typedef __attribute__((ext_vector_type(4))) float f32x4;
typedef __attribute__((ext_vector_type(16))) float f32x16;
typedef __attribute__((address_space(1))) void gvoid;
typedef __attribute__((address_space(3))) void svoid;

__device__ __forceinline__ float sigm(float v) { return 1.0f / (1.0f + __expf(-v)); }

// ---------------- weight pack: fp32 -> bf16, gate/up interleaved by 32 rows ----------------
// wgu (2048 rows x 256): rows t*64+0..31 = gate f=t*32..+31, rows t*64+32..63 = up (same f).
// 32-row groups so a 32x32 MFMA B-tile is pure gate or pure up, pairs in the SAME lane.
__global__ __launch_bounds__(256) void wconv_kernel(const float* __restrict__ g,
                                                    const float* __restrict__ u,
                                                    const float* __restrict__ dn,
                                                    __hip_bfloat16* __restrict__ wgu,
                                                    __hip_bfloat16* __restrict__ dwb) {
    int i = blockIdx.x * 256 + threadIdx.x;   // 262144 elems
    int f = i >> 8, k = i & 255;
    int t = f >> 5, fi = f & 31;
    wgu[(size_t)(t * 64 + fi) * 256 + k]      = __float2bfloat16(g[i]);
    wgu[(size_t)(t * 64 + 32 + fi) * 256 + k] = __float2bfloat16(u[i]);
    dwb[i] = __float2bfloat16(dn[i]);
}

// ---------------- geometric product + mix + LayerNorm -> normed (bf16) ----------------
// One WAVE per token; per-blade LN partials sm[8]/sq[8] (R15-verified correct).
__global__ __launch_bounds__(256) void geo_ln_kernel(
    const float* __restrict__ x, const float* __restrict__ iw,
    const float* __restrict__ sg, const float* __restrict__ gg,
    const float* __restrict__ lnw, const float* __restrict__ lnb,
    __hip_bfloat16* __restrict__ nrm)
{
    static constexpr int CK[64] = {
        0,1,2,3,4,5,6,7,
        1,0,4,5,2,3,7,6,
        2,4,0,6,1,7,3,5,
        3,5,6,0,7,1,2,4,
        4,2,1,7,0,6,5,3,
        5,3,7,1,6,0,4,2,
        6,7,3,2,5,4,0,1,
        7,6,5,4,3,2,1,0};
    __shared__ float coefs[64];
    const int tid = threadIdx.x;
    const int lane = tid & 63;
    const int wv = tid >> 6;
    const int n = blockIdx.x * 4 + wv;       // grid = N_TOK/4
    if (tid < 64) coefs[tid] = sg[tid] * sigm(iw[tid]);
    __syncthreads();

    const float4* xp = reinterpret_cast<const float4*>(x + (size_t)n * (8 * D_BLADE)) + lane;
    float4 xa[8];
#pragma unroll
    for (int b = 0; b < 8; ++b) xa[b] = xp[b * 64];

    float geo[8][4] = {};
#pragma unroll
    for (int p = 0; p < 64; ++p) {
        const float cf = coefs[p];
        const float4 ai = xa[p >> 3];
        const float4 aj = xa[p & 7];
        geo[CK[p]][0] += cf * ai.x * aj.x;
        geo[CK[p]][1] += cf * ai.y * aj.y;
        geo[CK[p]][2] += cf * ai.z * aj.z;
        geo[CK[p]][3] += cf * ai.w * aj.w;
    }

    const float g = sigm(gg[0]);
    float mixed[8][4];
    float sm[8], sq[8];
#pragma unroll
    for (int b = 0; b < 8; ++b) {
        const float xe[4] = {xa[b].x, xa[b].y, xa[b].z, xa[b].w};
        float s = 0.f, q = 0.f;
#pragma unroll
        for (int e = 0; e < 4; ++e) {
            float m = g * geo[b][e] + (1.0f - g) * xe[e];
            mixed[b][e] = m;
            s += m;
            q += m * m;
        }
        sm[b] = s;
        sq[b] = q;
    }
#pragma unroll
    for (int off = 32; off > 0; off >>= 1) {
#pragma unroll
        for (int b = 0; b < 8; ++b) {
            sm[b] += __shfl_xor(sm[b], off, 64);
            sq[b] += __shfl_xor(sq[b], off, 64);
        }
    }

    const float4 lw4 = reinterpret_cast<const float4*>(lnw)[lane];
    const float4 lb4 = reinterpret_cast<const float4*>(lnb)[lane];
    const float lwe[4] = {lw4.x, lw4.y, lw4.z, lw4.w};
    const float lbe[4] = {lb4.x, lb4.y, lb4.z, lb4.w};
#pragma unroll
    for (int b = 0; b < 8; ++b) {
        const float mu = sm[b] * (1.0f / 256.0f);
        const float var = sq[b] * (1.0f / 256.0f) - mu * mu;
        const float rs = rsqrtf(var + 1e-5f);
        short4_t o;
#pragma unroll
        for (int e = 0; e < 4; ++e) {
            __hip_bfloat16 v = __float2bfloat16((mixed[b][e] - mu) * rs * lwe[e] + lbe[e]);
            o[e] = *reinterpret_cast<short*>(&v);
        }
        *reinterpret_cast<short4_t*>(nrm + (size_t)n * (8 * D_BLADE) + b * D_BLADE + lane * 4) = o;
    }
}

// ============ GEMM building blocks (R8/R13-proven) ============
// XOR-swizzle byte X -> X ^ ((row&7)<<4) on 128B rows; staged linear via
// global_load_lds w=16 with inverse-swizzled global source (conflicts = 0).

#define STAGE(dst, srcbase, rowstride, kofs, NLOADS)                                 \
    _Pragma("unroll")                                                                 \
    for (int i = 0; i < (NLOADS); ++i) {                                              \
        int L = i * 4096 + tid * 16;                                                  \
        int r = L >> 7;                                                               \
        int Xs = (L & 127) ^ ((r & 7) << 4);                                          \
        const __hip_bfloat16* sp = (srcbase) + (size_t)(r) * (rowstride) + (kofs) + (Xs >> 1); \
        __builtin_amdgcn_global_load_lds((gvoid*)sp, (svoid*)((dst) + L), 16, 0, 0);  \
    }

// ---------------- gate/up GEMM + silu*mul epilogue -> h  (32x32x16 MFMA) ----------------
// Tile 128x128, BK=64, 4 waves (2x2), wave tile 64x64 = 2x2 of 32x32, acc 2x2xf32x16.
// Same LDS/staging/sync/occupancy as R13; ~33% fewer hot-loop instructions
// (16 MFMA + 16 ds_read per K-step vs 32+16) to attack the 93% issue saturation.
// A-frag: lane l holds row (l&31), k = (l>>5)*8 + e.  C/D: col=lane&31,
// row=(reg&3)+8*(reg>>2)+4*(lane>>5)  [m74/m101-verified].
__global__ __launch_bounds__(256, 4) void gu_kernel(
    const __hip_bfloat16* __restrict__ nrm,
    const __hip_bfloat16* __restrict__ wgu,
    __hip_bfloat16* __restrict__ h,
    int mbase)
{
    __shared__ char lds[32768];
    char* sA = lds;
    char* sB = lds + 16384;

    const int tid = threadIdx.x;
    const int l = tid & 63;
    const int w = tid >> 6;
    const int wm = w >> 1, wn = w & 1;
    const int lr = l & 31;          // row (A) / col (B) within 32-tile
    const int kh = l >> 5;          // k-half selector (8 elems each)
    const int rsw = (lr & 7) << 4;  // frag-row swizzle bits (row%8 == lr%8)

    const int cpx = gridDim.x >> 3;
    const int swz = (blockIdx.x & 7) * cpx + (blockIdx.x >> 3);
    const int bm = swz >> 4;
    const int n0 = (swz & 15) * 128;       // base wgu row
    const int m0 = mbase + bm * 128;
    const int hr0 = bm * 128;
    const __hip_bfloat16* An = nrm + (size_t)m0 * D_BLADE;
    const __hip_bfloat16* Bn = wgu + (size_t)n0 * D_BLADE;

    f32x16 acc[2][2];
#pragma unroll
    for (int mt = 0; mt < 2; ++mt)
#pragma unroll
        for (int nt = 0; nt < 2; ++nt)
#pragma unroll
            for (int e = 0; e < 16; ++e) acc[mt][nt][e] = 0.f;

    STAGE(sA, An, D_BLADE, 0, 4)
    STAGE(sB, Bn, D_BLADE, 0, 4)
    asm volatile("s_waitcnt vmcnt(0)" ::: "memory");
    __builtin_amdgcn_sched_barrier(0);
    __syncthreads();

    for (int c = 0; c < 4; ++c) {
#pragma unroll
        for (int ks = 0; ks < 4; ++ks) {
            const int cb = (ks * 32 + kh * 16) ^ rsw;
            bf16x8 a[2], b[2];
#pragma unroll
            for (int nt = 0; nt < 2; ++nt)
                b[nt] = *reinterpret_cast<const bf16x8*>(sB + (wn * 64 + nt * 32 + lr) * 128 + cb);
#pragma unroll
            for (int mt = 0; mt < 2; ++mt)
                a[mt] = *reinterpret_cast<const bf16x8*>(sA + (wm * 64 + mt * 32 + lr) * 128 + cb);
            __builtin_amdgcn_s_setprio(1);
#pragma unroll
            for (int mt = 0; mt < 2; ++mt)
#pragma unroll
                for (int nt = 0; nt < 2; ++nt)
                    acc[mt][nt] = __builtin_amdgcn_mfma_f32_32x32x16_bf16(a[mt], b[nt], acc[mt][nt], 0, 0, 0);
            __builtin_amdgcn_s_setprio(0);
        }
        __syncthreads();
        if (c < 3) {
            STAGE(sA, An, D_BLADE, (c + 1) * 64, 4)
            STAGE(sB, Bn, D_BLADE, (c + 1) * 64, 4)
            asm volatile("s_waitcnt vmcnt(0)" ::: "memory");
            __builtin_amdgcn_sched_barrier(0);
            __syncthreads();
        }
    }

    // epilogue: nt=0 gate tile, nt=1 up tile (same f, same lane)
    const int fbase = (n0 >> 1) + wn * 32 + lr;
#pragma unroll
    for (int mt = 0; mt < 2; ++mt) {
        f32x16 gv = acc[mt][0];
        f32x16 uv = acc[mt][1];
#pragma unroll
        for (int r = 0; r < 16; ++r) {
            int row = hr0 + wm * 64 + mt * 32 + (r & 3) + 8 * (r >> 2) + 4 * kh;
            float ge = gv[r];
            float hv = ge * sigm(ge) * uv[r];
            h[(size_t)row * D_FFN + fbase] = __float2bfloat16(hv);
        }
    }
}

// ---------------- down GEMM + residual -> out (EXACT R16 version) ----------------
// Tile 128x256, acc 4x8, LDS 48KB, h read exactly once + bijective XCD swizzle.
__global__ __launch_bounds__(256, 2) void down_kernel(
    const __hip_bfloat16* __restrict__ h,
    const __hip_bfloat16* __restrict__ dwb,
    const float* __restrict__ x,
    float* __restrict__ out,
    int mbase)
{
    __shared__ char lds[49152];
    char* sA = lds;            // h tile [128][128B]
    char* sB = lds + 16384;    // dw tile [256][128B]

    const int tid = threadIdx.x;
    const int l = tid & 63;
    const int w = tid >> 6;
    const int wm = w >> 1, wn = w & 1;
    const int rr = l & 15;
    const int kq = l >> 4;
    const int rsw = (rr & 7) << 4;
    const int cpx = gridDim.x >> 3;
    const int bm = (blockIdx.x & 7) * cpx + (blockIdx.x >> 3);
    const int hr0 = bm * 128;
    const __hip_bfloat16* An = h + (size_t)hr0 * D_FFN;
    const __hip_bfloat16* Bn = dwb;

    const f32x4 zero = {0.f, 0.f, 0.f, 0.f};
    f32x4 acc[4][8];
#pragma unroll
    for (int mt = 0; mt < 4; ++mt)
#pragma unroll
        for (int nt = 0; nt < 8; ++nt) acc[mt][nt] = zero;

    STAGE(sA, An, D_FFN, 0, 4)
    STAGE(sB, Bn, D_FFN, 0, 8)
    asm volatile("s_waitcnt vmcnt(0)" ::: "memory");
    __builtin_amdgcn_sched_barrier(0);
    __syncthreads();

    for (int c = 0; c < 16; ++c) {
#pragma unroll
        for (int kk = 0; kk < 2; ++kk) {
            const int cb = (kk * 64 + kq * 16) ^ rsw;
            bf16x8 a[4], b[8];
#pragma unroll
            for (int nt = 0; nt < 8; ++nt)
                b[nt] = *reinterpret_cast<const bf16x8*>(sB + (wn * 128 + nt * 16 + rr) * 128 + cb);
#pragma unroll
            for (int mt = 0; mt < 4; ++mt)
                a[mt] = *reinterpret_cast<const bf16x8*>(sA + (wm * 64 + mt * 16 + rr) * 128 + cb);
            __builtin_amdgcn_s_setprio(1);
#pragma unroll
            for (int mt = 0; mt < 4; ++mt)
#pragma unroll
                for (int nt = 0; nt < 8; ++nt)
                    acc[mt][nt] = __builtin_amdgcn_mfma_f32_16x16x32_bf16(a[mt], b[nt], acc[mt][nt], 0, 0, 0);
            __builtin_amdgcn_s_setprio(0);
        }
        __syncthreads();
        if (c < 15) {
            STAGE(sA, An, D_FFN, (c + 1) * 64, 4)
            STAGE(sB, Bn, D_FFN, (c + 1) * 64, 8)
            asm volatile("s_waitcnt vmcnt(0)" ::: "memory");
            __builtin_amdgcn_sched_barrier(0);
            __syncthreads();
        }
    }

    // epilogue: residual add, f32 store
#pragma unroll
    for (int mt = 0; mt < 4; ++mt)
#pragma unroll
        for (int nt = 0; nt < 8; ++nt)
#pragma unroll
            for (int r = 0; r < 4; ++r) {
                int gm = mbase + hr0 + wm * 64 + mt * 16 + kq * 4 + r;
                int d = wn * 128 + nt * 16 + rr;
                size_t idx = (size_t)gm * D_BLADE + d;
                out[idx] = x[idx] + acc[mt][nt][r];
            }
}

extern "C" void kernel_launch(void* const* d_in, const int* in_sizes, int n_in,
                              void* d_out, int out_size, void* d_ws, size_t ws_size,
                              hipStream_t stream) {
    const float* x   = (const float*)d_in[0];
    const float* iw  = (const float*)d_in[1];
    const float* sg  = (const float*)d_in[2];
    const float* gg  = (const float*)d_in[3];
    const float* gwf = (const float*)d_in[4];
    const float* uwf = (const float*)d_in[5];
    const float* dwf = (const float*)d_in[6];
    const float* lnw = (const float*)d_in[7];
    const float* lnb = (const float*)d_in[8];
    float* out = (float*)d_out;

    char* ws = (char*)d_ws;
    __hip_bfloat16* nrm = (__hip_bfloat16*)ws;                       // 33.5 MB
    size_t off = (size_t)M_TOTAL * D_BLADE * 2;
    __hip_bfloat16* wgu = (__hip_bfloat16*)(ws + off);               // 1 MB
    off += (size_t)2 * D_FFN * D_BLADE * 2;
    __hip_bfloat16* dwb = (__hip_bfloat16*)(ws + off);               // 0.5 MB
    off += (size_t)D_FFN * D_BLADE * 2;
    __hip_bfloat16* h = (__hip_bfloat16*)(ws + off);

    int S = 1;
    while (S < 64 && off + ((size_t)M_TOTAL / S) * D_FFN * 2 > ws_size) S <<= 1;
    const int MS = M_TOTAL / S;

    wconv_kernel<<<dim3((D_FFN * D_BLADE) / 256), dim3(256), 0, stream>>>(gwf, uwf, dwf, wgu, dwb);
    geo_ln_kernel<<<dim3(N_TOK / 4), dim3(256), 0, stream>>>(x, iw, sg, gg, lnw, lnb, nrm);
    for (int s = 0; s < S; ++s) {
        gu_kernel<<<dim3((MS / 128) * 16), dim3(256), 0, stream>>>(nrm, wgu, h, s * MS);
        down_kernel<<<dim3(MS / 128), dim3(256), 0, stream>>>(h, dwb, x, out, s * MS);
    }
}

// Round 18
// 164.270 us; speedup vs baseline: 1.0754x; 1.0754x over previous
//
#include <hip/hip_runtime.h>
#include <hip/hip_bf16.h>

#define D_BLADE 256
#define D_FFN 1024
#define N_TOK 8192
#define M_TOTAL (N_TOK * 8)

typedef __attribute__((ext_vector_type(8))) short bf16x8;
typedef __attribute__((ext_vector_type(4))) short short4_t;
typedef __attribute__((ext_vector_type(4))) float f32x4;
typedef __attribute__((address_space(1))) void gvoid;
typedef __attribute__((address_space(3))) void svoid;

__device__ __forceinline__ float sigm(float v) { return 1.0f / (1.0f + __expf(-v)); }

// ---------------- weight pack: fp32 -> bf16, gate/up interleaved by 16 rows ----------------
// wgu (2048 rows x 256): rows t*32+0..15 = gate f=t*16..+15, rows t*32+16..31 = up (same f).
__global__ __launch_bounds__(256) void wconv_kernel(const float* __restrict__ g,
                                                    const float* __restrict__ u,
                                                    const float* __restrict__ dn,
                                                    __hip_bfloat16* __restrict__ wgu,
                                                    __hip_bfloat16* __restrict__ dwb) {
    int i = blockIdx.x * 256 + threadIdx.x;   // 262144 elems
    int f = i >> 8, k = i & 255;
    int t = f >> 4, fi = f & 15;
    wgu[(size_t)(t * 32 + fi) * 256 + k]      = __float2bfloat16(g[i]);
    wgu[(size_t)(t * 32 + 16 + fi) * 256 + k] = __float2bfloat16(u[i]);
    dwb[i] = __float2bfloat16(dn[i]);
}

// ---------------- geometric product + mix + LayerNorm -> normed (bf16) ----------------
// One WAVE per token: lane owns d = lane*4..lane*4+3 (float4 loads, short4 stores).
// LayerNorm is PER-BLADE over D=256: per-blade partials sm[8]/sq[8], butterfly-reduced.
// (R15-verified correct.)
__global__ __launch_bounds__(256) void geo_ln_kernel(
    const float* __restrict__ x, const float* __restrict__ iw,
    const float* __restrict__ sg, const float* __restrict__ gg,
    const float* __restrict__ lnw, const float* __restrict__ lnb,
    __hip_bfloat16* __restrict__ nrm)
{
    static constexpr int CK[64] = {
        0,1,2,3,4,5,6,7,
        1,0,4,5,2,3,7,6,
        2,4,0,6,1,7,3,5,
        3,5,6,0,7,1,2,4,
        4,2,1,7,0,6,5,3,
        5,3,7,1,6,0,4,2,
        6,7,3,2,5,4,0,1,
        7,6,5,4,3,2,1,0};
    __shared__ float coefs[64];
    const int tid = threadIdx.x;
    const int lane = tid & 63;
    const int wv = tid >> 6;
    const int n = blockIdx.x * 4 + wv;       // grid = N_TOK/4
    if (tid < 64) coefs[tid] = sg[tid] * sigm(iw[tid]);
    __syncthreads();

    const float4* xp = reinterpret_cast<const float4*>(x + (size_t)n * (8 * D_BLADE)) + lane;
    float4 xa[8];
#pragma unroll
    for (int b = 0; b < 8; ++b) xa[b] = xp[b * 64];

    float geo[8][4] = {};
#pragma unroll
    for (int p = 0; p < 64; ++p) {
        const float cf = coefs[p];
        const float4 ai = xa[p >> 3];
        const float4 aj = xa[p & 7];
        geo[CK[p]][0] += cf * ai.x * aj.x;
        geo[CK[p]][1] += cf * ai.y * aj.y;
        geo[CK[p]][2] += cf * ai.z * aj.z;
        geo[CK[p]][3] += cf * ai.w * aj.w;
    }

    const float g = sigm(gg[0]);
    float mixed[8][4];
    float sm[8], sq[8];
#pragma unroll
    for (int b = 0; b < 8; ++b) {
        const float xe[4] = {xa[b].x, xa[b].y, xa[b].z, xa[b].w};
        float s = 0.f, q = 0.f;
#pragma unroll
        for (int e = 0; e < 4; ++e) {
            float m = g * geo[b][e] + (1.0f - g) * xe[e];
            mixed[b][e] = m;
            s += m;
            q += m * m;
        }
        sm[b] = s;
        sq[b] = q;
    }
#pragma unroll
    for (int off = 32; off > 0; off >>= 1) {
#pragma unroll
        for (int b = 0; b < 8; ++b) {
            sm[b] += __shfl_xor(sm[b], off, 64);
            sq[b] += __shfl_xor(sq[b], off, 64);
        }
    }

    const float4 lw4 = reinterpret_cast<const float4*>(lnw)[lane];
    const float4 lb4 = reinterpret_cast<const float4*>(lnb)[lane];
    const float lwe[4] = {lw4.x, lw4.y, lw4.z, lw4.w};
    const float lbe[4] = {lb4.x, lb4.y, lb4.z, lb4.w};
#pragma unroll
    for (int b = 0; b < 8; ++b) {
        const float mu = sm[b] * (1.0f / 256.0f);
        const float var = sq[b] * (1.0f / 256.0f) - mu * mu;
        const float rs = rsqrtf(var + 1e-5f);
        short4_t o;
#pragma unroll
        for (int e = 0; e < 4; ++e) {
            __hip_bfloat16 v = __float2bfloat16((mixed[b][e] - mu) * rs * lwe[e] + lbe[e]);
            o[e] = *reinterpret_cast<short*>(&v);
        }
        *reinterpret_cast<short4_t*>(nrm + (size_t)n * (8 * D_BLADE) + b * D_BLADE + lane * 4) = o;
    }
}

// ============ GEMM building blocks (R8/R13-proven) ============
// XOR-swizzle byte X -> X ^ ((row&7)<<4) on 128B rows; staged linear via
// global_load_lds w=16 with inverse-swizzled global source (conflicts = 0).

#define STAGE(dst, srcbase, rowstride, kofs, NLOADS)                                 \
    _Pragma("unroll")                                                                 \
    for (int i = 0; i < (NLOADS); ++i) {                                              \
        int L = i * 4096 + tid * 16;                                                  \
        int r = L >> 7;                                                               \
        int Xs = (L & 127) ^ ((r & 7) << 4);                                          \
        const __hip_bfloat16* sp = (srcbase) + (size_t)(r) * (rowstride) + (kofs) + (Xs >> 1); \
        __builtin_amdgcn_global_load_lds((gvoid*)sp, (svoid*)((dst) + L), 16, 0, 0);  \
    }

// ---------------- gate/up GEMM + silu*mul epilogue -> h  (EXACT R13/R16 version) ----------------
// Tile 128x128, BK=64, 4 waves (2x2), acc 4x4, LDS 32KB, 4 blocks/CU, XCD swizzle.
__global__ __launch_bounds__(256, 4) void gu_kernel(
    const __hip_bfloat16* __restrict__ nrm,
    const __hip_bfloat16* __restrict__ wgu,
    __hip_bfloat16* __restrict__ h,
    int mbase)
{
    __shared__ char lds[32768];
    char* sA = lds;
    char* sB = lds + 16384;

    const int tid = threadIdx.x;
    const int l = tid & 63;
    const int w = tid >> 6;
    const int wm = w >> 1, wn = w & 1;
    const int rr = l & 15;
    const int kq = l >> 4;
    const int rsw = (rr & 7) << 4;

    const int cpx = gridDim.x >> 3;
    const int swz = (blockIdx.x & 7) * cpx + (blockIdx.x >> 3);
    const int bm = swz >> 4;
    const int n0 = (swz & 15) * 128;
    const int m0 = mbase + bm * 128;
    const int hr0 = bm * 128;
    const __hip_bfloat16* An = nrm + (size_t)m0 * D_BLADE;
    const __hip_bfloat16* Bn = wgu + (size_t)n0 * D_BLADE;

    const f32x4 zero = {0.f, 0.f, 0.f, 0.f};
    f32x4 acc[4][4];
#pragma unroll
    for (int mt = 0; mt < 4; ++mt)
#pragma unroll
        for (int nt = 0; nt < 4; ++nt) acc[mt][nt] = zero;

    STAGE(sA, An, D_BLADE, 0, 4)
    STAGE(sB, Bn, D_BLADE, 0, 4)
    asm volatile("s_waitcnt vmcnt(0)" ::: "memory");
    __builtin_amdgcn_sched_barrier(0);
    __syncthreads();

    for (int c = 0; c < 4; ++c) {
#pragma unroll
        for (int kk = 0; kk < 2; ++kk) {
            const int cb = (kk * 64 + kq * 16) ^ rsw;
            bf16x8 a[4], b[4];
#pragma unroll
            for (int nt = 0; nt < 4; ++nt)
                b[nt] = *reinterpret_cast<const bf16x8*>(sB + (wn * 64 + nt * 16 + rr) * 128 + cb);
#pragma unroll
            for (int mt = 0; mt < 4; ++mt)
                a[mt] = *reinterpret_cast<const bf16x8*>(sA + (wm * 64 + mt * 16 + rr) * 128 + cb);
            __builtin_amdgcn_s_setprio(1);
#pragma unroll
            for (int mt = 0; mt < 4; ++mt)
#pragma unroll
                for (int nt = 0; nt < 4; ++nt)
                    acc[mt][nt] = __builtin_amdgcn_mfma_f32_16x16x32_bf16(a[mt], b[nt], acc[mt][nt], 0, 0, 0);
            __builtin_amdgcn_s_setprio(0);
        }
        __syncthreads();
        if (c < 3) {
            STAGE(sA, An, D_BLADE, (c + 1) * 64, 4)
            STAGE(sB, Bn, D_BLADE, (c + 1) * 64, 4)
            asm volatile("s_waitcnt vmcnt(0)" ::: "memory");
            __builtin_amdgcn_sched_barrier(0);
            __syncthreads();
        }
    }

    // epilogue: nt even = gate tile, nt odd = up tile (same f, same lane)
#pragma unroll
    for (int mt = 0; mt < 4; ++mt)
#pragma unroll
        for (int ntp = 0; ntp < 2; ++ntp) {
            f32x4 gv = acc[mt][2 * ntp];
            f32x4 uv = acc[mt][2 * ntp + 1];
            const int fcol = ((n0 + wn * 64) >> 1) + ntp * 16 + rr;
#pragma unroll
            for (int r = 0; r < 4; ++r) {
                int row = hr0 + wm * 64 + mt * 16 + kq * 4 + r;
                float ge = gv[r];
                float hv = ge * sigm(ge) * uv[r];
                h[(size_t)row * D_FFN + fcol] = __float2bfloat16(hv);
            }
        }
}

// ---------------- down GEMM + residual -> out (full N=256 per block) ----------------
// Tile 128x256, acc 4x8, LDS 48KB, h read exactly once + bijective XCD swizzle.
__global__ __launch_bounds__(256, 2) void down_kernel(
    const __hip_bfloat16* __restrict__ h,
    const __hip_bfloat16* __restrict__ dwb,
    const float* __restrict__ x,
    float* __restrict__ out,
    int mbase)
{
    __shared__ char lds[49152];
    char* sA = lds;            // h tile [128][128B]
    char* sB = lds + 16384;    // dw tile [256][128B]

    const int tid = threadIdx.x;
    const int l = tid & 63;
    const int w = tid >> 6;
    const int wm = w >> 1, wn = w & 1;
    const int rr = l & 15;
    const int kq = l >> 4;
    const int rsw = (rr & 7) << 4;
    const int cpx = gridDim.x >> 3;
    const int bm = (blockIdx.x & 7) * cpx + (blockIdx.x >> 3);
    const int hr0 = bm * 128;
    const __hip_bfloat16* An = h + (size_t)hr0 * D_FFN;
    const __hip_bfloat16* Bn = dwb;

    const f32x4 zero = {0.f, 0.f, 0.f, 0.f};
    f32x4 acc[4][8];
#pragma unroll
    for (int mt = 0; mt < 4; ++mt)
#pragma unroll
        for (int nt = 0; nt < 8; ++nt) acc[mt][nt] = zero;

    STAGE(sA, An, D_FFN, 0, 4)
    STAGE(sB, Bn, D_FFN, 0, 8)
    asm volatile("s_waitcnt vmcnt(0)" ::: "memory");
    __builtin_amdgcn_sched_barrier(0);
    __syncthreads();

    for (int c = 0; c < 16; ++c) {
#pragma unroll
        for (int kk = 0; kk < 2; ++kk) {
            const int cb = (kk * 64 + kq * 16) ^ rsw;
            bf16x8 a[4], b[8];
#pragma unroll
            for (int nt = 0; nt < 8; ++nt)
                b[nt] = *reinterpret_cast<const bf16x8*>(sB + (wn * 128 + nt * 16 + rr) * 128 + cb);
#pragma unroll
            for (int mt = 0; mt < 4; ++mt)
                a[mt] = *reinterpret_cast<const bf16x8*>(sA + (wm * 64 + mt * 16 + rr) * 128 + cb);
            __builtin_amdgcn_s_setprio(1);
#pragma unroll
            for (int mt = 0; mt < 4; ++mt)
#pragma unroll
                for (int nt = 0; nt < 8; ++nt)
                    acc[mt][nt] = __builtin_amdgcn_mfma_f32_16x16x32_bf16(a[mt], b[nt], acc[mt][nt], 0, 0, 0);
            __builtin_amdgcn_s_setprio(0);
        }
        __syncthreads();
        if (c < 15) {
            STAGE(sA, An, D_FFN, (c + 1) * 64, 4)
            STAGE(sB, Bn, D_FFN, (c + 1) * 64, 8)
            asm volatile("s_waitcnt vmcnt(0)" ::: "memory");
            __builtin_amdgcn_sched_barrier(0);
            __syncthreads();
        }
    }

    // epilogue: residual add, f32 store
#pragma unroll
    for (int mt = 0; mt < 4; ++mt)
#pragma unroll
        for (int nt = 0; nt < 8; ++nt)
#pragma unroll
            for (int r = 0; r < 4; ++r) {
                int gm = mbase + hr0 + wm * 64 + mt * 16 + kq * 4 + r;
                int d = wn * 128 + nt * 16 + rr;
                size_t idx = (size_t)gm * D_BLADE + d;
                out[idx] = x[idx] + acc[mt][nt][r];
            }
}

extern "C" void kernel_launch(void* const* d_in, const int* in_sizes, int n_in,
                              void* d_out, int out_size, void* d_ws, size_t ws_size,
                              hipStream_t stream) {
    const float* x   = (const float*)d_in[0];
    const float* iw  = (const float*)d_in[1];
    const float* sg  = (const float*)d_in[2];
    const float* gg  = (const float*)d_in[3];
    const float* gwf = (const float*)d_in[4];
    const float* uwf = (const float*)d_in[5];
    const float* dwf = (const float*)d_in[6];
    const float* lnw = (const float*)d_in[7];
    const float* lnb = (const float*)d_in[8];
    float* out = (float*)d_out;

    char* ws = (char*)d_ws;
    __hip_bfloat16* nrm = (__hip_bfloat16*)ws;                       // 33.5 MB
    size_t off = (size_t)M_TOTAL * D_BLADE * 2;
    __hip_bfloat16* wgu = (__hip_bfloat16*)(ws + off);               // 1 MB
    off += (size_t)2 * D_FFN * D_BLADE * 2;
    __hip_bfloat16* dwb = (__hip_bfloat16*)(ws + off);               // 0.5 MB
    off += (size_t)D_FFN * D_BLADE * 2;
    __hip_bfloat16* h = (__hip_bfloat16*)(ws + off);

    int S = 1;
    while (S < 64 && off + ((size_t)M_TOTAL / S) * D_FFN * 2 > ws_size) S <<= 1;
    const int MS = M_TOTAL / S;

    wconv_kernel<<<dim3((D_FFN * D_BLADE) / 256), dim3(256), 0, stream>>>(gwf, uwf, dwf, wgu, dwb);
    geo_ln_kernel<<<dim3(N_TOK / 4), dim3(256), 0, stream>>>(x, iw, sg, gg, lnw, lnb, nrm);
    for (int s = 0; s < S; ++s) {
        gu_kernel<<<dim3((MS / 128) * 16), dim3(256), 0, stream>>>(nrm, wgu, h, s * MS);
        down_kernel<<<dim3(MS / 128), dim3(256), 0, stream>>>(h, dwb, x, out, s * MS);
    }
}